// Round 7
// baseline (1976.257 us; speedup 1.0000x reference)
//
#include <hip/hip_runtime.h>
#include <cstdint>
#include <cstddef>

typedef __attribute__((ext_vector_type(8))) __bf16 bf16x8;
typedef __attribute__((ext_vector_type(8))) unsigned short u16x8;
typedef __attribute__((ext_vector_type(4))) unsigned short u16x4;
typedef __attribute__((ext_vector_type(2))) unsigned short u16x2;
typedef __attribute__((ext_vector_type(4))) float f32x4;
typedef __attribute__((ext_vector_type(2))) float f32x2;

// ---- helpers -------------------------------------------------------------
__device__ __forceinline__ unsigned short f2bf(float f){
  unsigned int u = __float_as_uint(f);
  u += 0x7FFFu + ((u >> 16) & 1u);          // round to nearest even
  return (unsigned short)(u >> 16);
}
__device__ __forceinline__ float bf2f(unsigned short s){
  return __uint_as_float(((unsigned int)s) << 16);
}
__device__ __forceinline__ float sigm(float x){ return 1.f/(1.f + __expf(-x)); }
__device__ __forceinline__ float tanh_f(float x){ float e = __expf(2.f*x); return 1.f - 2.f/(e + 1.f); }
__device__ __forceinline__ f32x4 mfma16(u16x8 a, u16x8 b, f32x4 c){
  return __builtin_amdgcn_mfma_f32_16x16x32_bf16(
      __builtin_bit_cast(bf16x8, a), __builtin_bit_cast(bf16x8, b), c, 0, 0, 0);
}

// B=1024, T=128, F=128, H=256
// Per step: S = h(16x256 per WG) @ Wc(256x1024); gate g columns [g*256,(g+1)*256):
//   g=0: Wih_h_r + Whh_r ; g=1: Wih_h_z + Whh_z ; g=2: Wih_h_n ; g=3: Whh_n
// seq5: 64 WGs x 1024 thr (16 waves), 16 batch rows/WG, 1 WG/CU.
//   FULL weight residency: wave w owns nt {w,16+w,32+w,48+w} (one per gate),
//   4 nt x 8 ks = 32 u16x8 chunks = 128 VGPR/wave; 16 waves = all 512 KB of Wc
//   in the CU register file. asm-pinned so the allocator cannot rematerialize
//   the loads inside the t-loop (round-6 failure: VGPR_Count=128 proved remat).
//   LDS = hsw only (8 KB). 2 barriers/step.

__device__ __forceinline__ float wcval(int g, int n, int k,
    const float* __restrict__ Wih, const float* __restrict__ Whh){
  if (g==0) return Wih[n*512 + 128+k]       + Whh[n*256 + k];
  if (g==1) return Wih[(256+n)*512 + 128+k] + Whh[(256+n)*256 + k];
  if (g==2) return Wih[(512+n)*512 + 128+k];
  return Whh[(512+n)*256 + k];
}

// ---- weight prep ---------------------------------------------------------
// WrAll   : (((w*4+g)*8+ks)*64 + lane)*8 + j   (262144 elems, 512 KB)
//           chunk (w,g,ks): B-frag of Wc gate g, cols w*16..w*16+15, k ks*32..+31
// W2_sw   : [nt(48)][ks(8)][lane(64)][8]
// Wdh_sw  : [nt(16)][ks(4)][lane(64)][8]
__global__ __launch_bounds__(256) void kw(
    const float* __restrict__ Wdh, const float* __restrict__ Wih,
    const float* __restrict__ Whh, const float* __restrict__ bih,
    const float* __restrict__ bhh,
    unsigned short* __restrict__ WrAll,
    unsigned short* __restrict__ W2,
    unsigned short* __restrict__ Wd, float* __restrict__ b2){
  int i0 = blockIdx.x*256 + threadIdx.x;
  int stride = gridDim.x*256;
  for (int idx=i0; idx<262144; idx+=stride){          // WrAll (all 8 ks)
    int j = idx&7, l=(idx>>3)&63, r=idx>>9;           // r < 512
    int ks = r&7, r2 = r>>3;                          // r2 = w*4+g
    int g = r2&3, w = r2>>2;
    int n = w*16 + (l&15);                            // within-gate col [0,256)
    int k = ks*32 + ((l>>4)<<3) + j;
    WrAll[idx] = f2bf(wcval(g, n, k, Wih, Whh));
  }
  for (int idx=i0; idx<196608; idx+=stride){
    int j=idx&7, l=(idx>>3)&63, ks=(idx>>9)&7, nt=idx>>12;
    int n = nt*16 + (l&15);
    int k = ks*32 + ((l>>4)<<3) + j;
    float v = (k<128) ? Wih[n*512 + k] : Wih[n*512 + 256 + k];
    W2[idx] = f2bf(v);
  }
  for (int idx=i0; idx<32768; idx+=stride){
    int j=idx&7, l=(idx>>3)&63, ks=(idx>>9)&3, nt=idx>>11;
    int n = nt*16 + (l&15);
    int k = ks*32 + ((l>>4)<<3) + j;
    Wd[idx] = f2bf(Wdh[n*128 + k]);
  }
  for (int idx=i0; idx<768; idx+=stride)
    b2[idx] = bih[idx] + (idx<512 ? bhh[idx] : 0.f);
}

// ---- elementwise prep: Apre=[x_in|m] (T,B,256) bf16 ; Dt=(T,B,128) bf16 --
__global__ __launch_bounds__(256) void kprep(
    const float* __restrict__ X, const float* __restrict__ M,
    const float* __restrict__ D, const float* __restrict__ mu,
    const float* __restrict__ Xl, const float* __restrict__ Wdx,
    const float* __restrict__ bdx,
    unsigned short* __restrict__ Apre, unsigned short* __restrict__ Dt){
  int lane = threadIdx.x & 63;
  int wave = (blockIdx.x*256 + threadIdx.x) >> 6;
  int c0 = lane*2;
  float dg0 = Wdx[c0*128 + c0];
  float dg1 = Wdx[(c0+1)*128 + (c0+1)];
  float bx0 = bdx[c0], bx1 = bdx[c0+1];
  for (int r = wave; r < 131072; r += 4096){
    int t = r>>10, b = r&1023;
    size_t src = ((size_t)b*128 + t)*128 + c0;
    f32x2 x  = *(const f32x2*)(X+src);
    f32x2 m  = *(const f32x2*)(M+src);
    f32x2 d  = *(const f32x2*)(D+src);
    f32x2 xl = *(const f32x2*)(Xl+src);
    f32x2 mb = *(const f32x2*)(mu + b*128 + c0);
    float g0 = __expf(-fmaxf(0.f, d.x*dg0 + bx0));
    float g1 = __expf(-fmaxf(0.f, d.y*dg1 + bx1));
    float xh0 = g0*xl.x + (1.f-g0)*mb.x;
    float xh1 = g1*xl.y + (1.f-g1)*mb.y;
    float xi0 = m.x*x.x + (1.f-m.x)*xh0;
    float xi1 = m.y*x.y + (1.f-m.y)*xh1;
    size_t ar = (size_t)r*256;
    *(u16x2*)(Apre + ar + c0)        = u16x2{f2bf(xi0), f2bf(xi1)};
    *(u16x2*)(Apre + ar + 128 + c0)  = u16x2{f2bf(m.x), f2bf(m.y)};
    *(u16x2*)(Dt + (size_t)r*128 + c0) = u16x2{f2bf(d.x), f2bf(d.y)};
  }
}

// ---- batched activation GEMM (unchanged, verified) -----------------------
template<int KS, int NTOT, int PNT, int MODE>
__global__ __launch_bounds__(256) void gemm_act(
    const unsigned short* __restrict__ A, const unsigned short* __restrict__ Bw,
    const float* __restrict__ bias, unsigned short* __restrict__ out){
  const int N = NTOT*16;
  int lane = threadIdx.x & 63;
  int wid  = threadIdx.x >> 6;
  int gw   = blockIdx.x*4 + wid;
  size_t rb = (size_t)gw*32;
  int lr = lane&15, lk = (lane>>4)<<3, lq = (lane>>4)<<2;
  u16x8 a[2][KS];
  #pragma unroll
  for (int mt=0; mt<2; ++mt)
    #pragma unroll
    for (int ks=0; ks<KS; ++ks)
      a[mt][ks] = *(const u16x8*)&A[(rb + mt*16 + lr)*(KS*32) + ks*32 + lk];
  #pragma unroll
  for (int p=0; p<NTOT/PNT; ++p){
    f32x4 acc[2][PNT];
    #pragma unroll
    for (int mt=0; mt<2; ++mt)
      #pragma unroll
      for (int i=0; i<PNT; ++i) acc[mt][i] = f32x4{0.f,0.f,0.f,0.f};
    #pragma unroll
    for (int ks=0; ks<KS; ++ks){
      #pragma unroll
      for (int i=0; i<PNT; ++i){
        int nt = p*PNT + i;
        u16x8 b = *(const u16x8*)&Bw[((size_t)(nt*KS + ks)*64 + lane)*8];
        acc[0][i] = mfma16(a[0][ks], b, acc[0][i]);
        acc[1][i] = mfma16(a[1][ks], b, acc[1][i]);
      }
    }
    #pragma unroll
    for (int i=0; i<PNT; ++i){
      int nt = p*PNT + i; int col = nt*16 + lr;
      float bv = bias[col];
      #pragma unroll
      for (int mt=0; mt<2; ++mt){
        #pragma unroll
        for (int q=0; q<4; ++q){
          size_t row = rb + mt*16 + lq + q;
          float v = acc[mt][i][q] + bv;
          if (MODE==1) v = __expf(-fmaxf(0.f, v));
          out[row*N + col] = f2bf(v);
        }
      }
    }
  }
}

// ---- persistent sequential kernel: FULL VGPR weight residency ------------
__global__ __launch_bounds__(1024, 4) void seq5(
    const unsigned short* __restrict__ WrAll,
    const unsigned short* __restrict__ gamma, const unsigned short* __restrict__ gipre,
    const float* __restrict__ bhh, float* __restrict__ out){
  __shared__ unsigned short hsw[4096];    // 8 KB: A-fragment-ordered h (bf16)
  const int tid  = threadIdx.x;
  const int lane = tid & 63;
  const int w    = tid >> 6;              // 0..15
  const int bbase = blockIdx.x * 16;
  const int lr   = lane & 15;
  const int lq4  = (lane >> 4) << 2;      // row quad base 0/4/8/12
  const int col  = w*16 + lr;             // 0..255 (within-gate col)

  // ---- prologue: the ENTIRE Wc in VGPRs (32 chunks/wave x 16 waves) ----
  u16x8 Wr[4][8];
  #pragma unroll
  for (int g=0; g<4; ++g)
    #pragma unroll
    for (int ks=0; ks<8; ++ks)
      Wr[g][ks] = *(const u16x8*)&WrAll[(((w*4+g)*8+ks)*64 + lane)*8];
  // pin: make each chunk an opaque asm-defined value -> cannot be
  // rematerialized as an in-loop load (round-6 failure mode)
  #pragma unroll
  for (int g=0; g<4; ++g)
    #pragma unroll
    for (int ks=0; ks<8; ++ks)
      asm volatile("" : "+v"(Wr[g][ks]));

  float h_reg[4];
  #pragma unroll
  for (int q=0; q<4; ++q) h_reg[q] = 0.f;
  const float bnn = bhh[512 + col];

  // hsw write addresses for the 4 owned (row,col) elems
  int sh[4];
  #pragma unroll
  for (int q=0; q<4; ++q)
    sh[q] = (col>>5)*512 + ((lq4+q) + (((col>>3)&3)<<4))*8 + (col&7);

  unsigned short g_pre[4];
  #pragma unroll
  for (int q=0; q<4; ++q)
    g_pre[q] = gamma[((size_t)(bbase + lq4 + q))*256 + col];

  for (int t = 0; t < 128; ++t){
    // ---- phase 1: decay h, emit rep, publish A-fragments ----
    #pragma unroll
    for (int q=0; q<4; ++q){
      float hd = h_reg[q] * bf2f(g_pre[q]);
      out[((size_t)(bbase+lq4+q)*128 + t)*256 + col] = hd;
      h_reg[q] = hd;
      hsw[sh[q]] = f2bf(hd);
    }
    __syncthreads();   // S1: hsw ready

    // issue gipre loads early; consumed after the MFMA phase (~2500 cy later)
    const unsigned short* gp = gipre + ((size_t)t*1024 + bbase)*768 + col;
    unsigned short gv[3][4];
    #pragma unroll
    for (int g3=0; g3<3; ++g3)
      #pragma unroll
      for (int q=0; q<4; ++q)
        gv[g3][q] = gp[(size_t)(lq4+q)*768 + g3*256];

    // ---- MFMA phase: 32 MFMAs/wave, weights all in registers ----
    f32x4 acc[4];
    #pragma unroll
    for (int g=0; g<4; ++g) acc[g] = f32x4{0.f,0.f,0.f,0.f};
    #pragma unroll
    for (int ks=0; ks<8; ++ks){
      u16x8 a = *(const u16x8*)&hsw[ks*512 + lane*8];
      #pragma unroll
      for (int g=0; g<4; ++g)
        acc[g] = mfma16(a, Wr[g][ks], acc[g]);
    }
    __syncthreads();   // S2: all hsw A-reads done -> next phase1 may overwrite

    // ---- gate phase (in-register; all 4 gates live in this wave) ----
    #pragma unroll
    for (int q=0; q<4; ++q){
      float gr = bf2f(gv[0][q]);
      float gz = bf2f(gv[1][q]);
      float gn = bf2f(gv[2][q]);
      float rr = sigm(gr + acc[0][q]);
      float zz = sigm(gz + acc[1][q]);
      float nv = tanh_f(gn + acc[2][q] + rr*(acc[3][q] + bnn));
      float hn = (1.f-zz)*nv + zz*h_reg[q];
      h_reg[q] = hn;
      if (t == 127) out[(size_t)33554432 + (size_t)(bbase+lq4+q)*256 + col] = hn;
    }
    // prefetch next step's gamma (covered by gate VALU + next phase1)
    if (t < 127){
      #pragma unroll
      for (int q=0; q<4; ++q)
        g_pre[q] = gamma[((size_t)(t+1)*1024 + bbase + lq4 + q)*256 + col];
    }
  }
}

// ---- host glue -----------------------------------------------------------
extern "C" void kernel_launch(void* const* d_in, const int* in_sizes, int n_in,
                              void* d_out, int out_size, void* d_ws, size_t ws_size,
                              hipStream_t stream){
  (void)in_sizes; (void)n_in; (void)out_size; (void)ws_size;
  const float* X   = (const float*)d_in[0];
  const float* M   = (const float*)d_in[1];
  const float* D   = (const float*)d_in[2];
  const float* mu  = (const float*)d_in[3];
  const float* Xl  = (const float*)d_in[4];
  const float* Wdh = (const float*)d_in[5];
  const float* bdh = (const float*)d_in[6];
  const float* Wdx = (const float*)d_in[7];
  const float* bdx = (const float*)d_in[8];
  const float* Wih = (const float*)d_in[9];
  const float* Whh = (const float*)d_in[10];
  const float* bih = (const float*)d_in[11];
  const float* bhh = (const float*)d_in[12];
  float* out = (float*)d_out;
  char* ws = (char*)d_ws;

  // workspace layout
  unsigned short* gipre = (unsigned short*)ws;                      // 201326592 B
  unsigned short* gamma = (unsigned short*)(ws + 201326592);        //  67108864 B
  unsigned short* W2sw  = (unsigned short*)(ws + 268435456);        //    393216 B
  unsigned short* Wdsw  = (unsigned short*)(ws + 268828672);        //     65536 B
  unsigned short* WrAll = (unsigned short*)(ws + 268894208);        //    524288 B
  float*          b2    = (float*)        (ws + 269418496);         //      3072 B
  // Apre (67.1MB) + Dt (33.6MB) staged inside d_out: fully consumed by the
  // GEMMs below BEFORE seq5 writes the real outputs (same-stream ordering).
  unsigned short* Apre = (unsigned short*)d_out;
  unsigned short* Dt   = (unsigned short*)((char*)d_out + 67108864);

  kw<<<256, 256, 0, stream>>>(Wdh, Wih, Whh, bih, bhh, WrAll, W2sw, Wdsw, b2);
  kprep<<<1024, 256, 0, stream>>>(X, M, D, mu, Xl, Wdx, bdx, Apre, Dt);
  gemm_act<4,16,8,1><<<1024, 256, 0, stream>>>(Dt, Wdsw, bdh, gamma);
  gemm_act<8,48,8,0><<<1024, 256, 0, stream>>>(Apre, W2sw, b2, gipre);
  seq5<<<64, 1024, 0, stream>>>(WrAll, gamma, gipre, bhh, out);
}

// Round 8
// 1292.142 us; speedup vs baseline: 1.5294x; 1.5294x over previous
//
#include <hip/hip_runtime.h>
#include <cstdint>
#include <cstddef>

typedef __attribute__((ext_vector_type(8))) __bf16 bf16x8;
typedef __attribute__((ext_vector_type(8))) unsigned short u16x8;
typedef __attribute__((ext_vector_type(4))) unsigned short u16x4;
typedef __attribute__((ext_vector_type(2))) unsigned short u16x2;
typedef __attribute__((ext_vector_type(4))) float f32x4;
typedef __attribute__((ext_vector_type(2))) float f32x2;

// ---- helpers -------------------------------------------------------------
__device__ __forceinline__ unsigned short f2bf(float f){
  unsigned int u = __float_as_uint(f);
  u += 0x7FFFu + ((u >> 16) & 1u);          // round to nearest even
  return (unsigned short)(u >> 16);
}
__device__ __forceinline__ float bf2f(unsigned short s){
  return __uint_as_float(((unsigned int)s) << 16);
}
__device__ __forceinline__ float sigm(float x){ return 1.f/(1.f + __expf(-x)); }
__device__ __forceinline__ float tanh_f(float x){ float e = __expf(2.f*x); return 1.f - 2.f/(e + 1.f); }
__device__ __forceinline__ f32x4 mfma16(u16x8 a, u16x8 b, f32x4 c){
  return __builtin_amdgcn_mfma_f32_16x16x32_bf16(
      __builtin_bit_cast(bf16x8, a), __builtin_bit_cast(bf16x8, b), c, 0, 0, 0);
}

// B=1024, T=128, F=128, H=256
// Per step: S = h(16x256 per WG) @ Wc(256x1024); gate g cols [g*256,(g+1)*256):
//   g=0: Wih_h_r + Whh_r ; g=1: Wih_h_z + Whh_z ; g=2: Wih_h_n ; g=3: Whh_n
// seq6: 64 WGs x 512 thr (8 waves, cap 256 VGPR), 16 rows/WG, 1 WG/CU.
//   Wave w owns 8 nt: (g,c) g=0..3, c=0..1 -> within-gate cols w*32+c*16..+15.
//   Residency: ks0..2 VGPR (24 chunks=96 regs/wave, asm-pinned; feasible at
//   cap 256 - round 7 failed because 1024-thr blocks cap VGPR at 128 < Wr).
//   ks3..4 dynamic LDS (128 chunks = 128 KB, loaded once - can't remat).
//   ks5..7 streamed (192 KB/step/CU) via 6-deep rolling register buffer.

__device__ __forceinline__ float wcval(int g, int n, int k,
    const float* __restrict__ Wih, const float* __restrict__ Whh){
  if (g==0) return Wih[n*512 + 128+k]       + Whh[n*256 + k];
  if (g==1) return Wih[(256+n)*512 + 128+k] + Whh[(256+n)*256 + k];
  if (g==2) return Wih[(512+n)*512 + 128+k];
  return Whh[(512+n)*256 + k];
}

// ---- weight prep ---------------------------------------------------------
// WrG  : (((w*8+g*2+c)*3+ks )*64+l)*8+j  ks=0..2   (98304 elems, 192 KB)
// WldsG: (((w*8+g*2+c)*2+ks2)*64+l)*8+j  ks=3+ks2  (65536 elems, 128 KB)
// WstrG: (((w*8+g*2+c)*3+ksi)*64+l)*8+j  ks=5+ksi  (98304 elems, 192 KB)
// all with n = (w*2+c)*16 + (l&15)  [within-gate col], k = ks*32+((l>>4)<<3)+j
__global__ __launch_bounds__(256) void kw(
    const float* __restrict__ Wdh, const float* __restrict__ Wih,
    const float* __restrict__ Whh, const float* __restrict__ bih,
    const float* __restrict__ bhh,
    unsigned short* __restrict__ WrG, unsigned short* __restrict__ WldsG,
    unsigned short* __restrict__ WstrG,
    unsigned short* __restrict__ W2,
    unsigned short* __restrict__ Wd, float* __restrict__ b2){
  int i0 = blockIdx.x*256 + threadIdx.x;
  int stride = gridDim.x*256;
  for (int idx=i0; idx<98304; idx+=stride){           // WrG (ks 0..2)
    int j=idx&7, l=(idx>>3)&63, r=idx>>9;             // r < 192
    int ks=r%3, r2=r/3;                               // r2 = w*8+g*2+c
    int c=r2&1, g=(r2>>1)&3, w=r2>>3;
    int n = (w*2+c)*16 + (l&15);
    int k = ks*32 + ((l>>4)<<3) + j;
    WrG[idx] = f2bf(wcval(g, n, k, Wih, Whh));
  }
  for (int idx=i0; idx<65536; idx+=stride){           // WldsG (ks 3..4)
    int j=idx&7, l=(idx>>3)&63, r=idx>>9;             // r < 128
    int ks2=r&1, r2=r>>1;
    int c=r2&1, g=(r2>>1)&3, w=r2>>3;
    int n = (w*2+c)*16 + (l&15);
    int k = (3+ks2)*32 + ((l>>4)<<3) + j;
    WldsG[idx] = f2bf(wcval(g, n, k, Wih, Whh));
  }
  for (int idx=i0; idx<98304; idx+=stride){           // WstrG (ks 5..7)
    int j=idx&7, l=(idx>>3)&63, r=idx>>9;             // r < 192
    int ksi=r%3, r2=r/3;
    int c=r2&1, g=(r2>>1)&3, w=r2>>3;
    int n = (w*2+c)*16 + (l&15);
    int k = (5+ksi)*32 + ((l>>4)<<3) + j;
    WstrG[idx] = f2bf(wcval(g, n, k, Wih, Whh));
  }
  for (int idx=i0; idx<196608; idx+=stride){
    int j=idx&7, l=(idx>>3)&63, ks=(idx>>9)&7, nt=idx>>12;
    int n = nt*16 + (l&15);
    int k = ks*32 + ((l>>4)<<3) + j;
    float v = (k<128) ? Wih[n*512 + k] : Wih[n*512 + 256 + k];
    W2[idx] = f2bf(v);
  }
  for (int idx=i0; idx<32768; idx+=stride){
    int j=idx&7, l=(idx>>3)&63, ks=(idx>>9)&3, nt=idx>>11;
    int n = nt*16 + (l&15);
    int k = ks*32 + ((l>>4)<<3) + j;
    Wd[idx] = f2bf(Wdh[n*128 + k]);
  }
  for (int idx=i0; idx<768; idx+=stride)
    b2[idx] = bih[idx] + (idx<512 ? bhh[idx] : 0.f);
}

// ---- elementwise prep: Apre=[x_in|m] (T,B,256) bf16 ; Dt=(T,B,128) bf16 --
__global__ __launch_bounds__(256) void kprep(
    const float* __restrict__ X, const float* __restrict__ M,
    const float* __restrict__ D, const float* __restrict__ mu,
    const float* __restrict__ Xl, const float* __restrict__ Wdx,
    const float* __restrict__ bdx,
    unsigned short* __restrict__ Apre, unsigned short* __restrict__ Dt){
  int lane = threadIdx.x & 63;
  int wave = (blockIdx.x*256 + threadIdx.x) >> 6;
  int c0 = lane*2;
  float dg0 = Wdx[c0*128 + c0];
  float dg1 = Wdx[(c0+1)*128 + (c0+1)];
  float bx0 = bdx[c0], bx1 = bdx[c0+1];
  for (int r = wave; r < 131072; r += 4096){
    int t = r>>10, b = r&1023;
    size_t src = ((size_t)b*128 + t)*128 + c0;
    f32x2 x  = *(const f32x2*)(X+src);
    f32x2 m  = *(const f32x2*)(M+src);
    f32x2 d  = *(const f32x2*)(D+src);
    f32x2 xl = *(const f32x2*)(Xl+src);
    f32x2 mb = *(const f32x2*)(mu + b*128 + c0);
    float g0 = __expf(-fmaxf(0.f, d.x*dg0 + bx0));
    float g1 = __expf(-fmaxf(0.f, d.y*dg1 + bx1));
    float xh0 = g0*xl.x + (1.f-g0)*mb.x;
    float xh1 = g1*xl.y + (1.f-g1)*mb.y;
    float xi0 = m.x*x.x + (1.f-m.x)*xh0;
    float xi1 = m.y*x.y + (1.f-m.y)*xh1;
    size_t ar = (size_t)r*256;
    *(u16x2*)(Apre + ar + c0)        = u16x2{f2bf(xi0), f2bf(xi1)};
    *(u16x2*)(Apre + ar + 128 + c0)  = u16x2{f2bf(m.x), f2bf(m.y)};
    *(u16x2*)(Dt + (size_t)r*128 + c0) = u16x2{f2bf(d.x), f2bf(d.y)};
  }
}

// ---- batched activation GEMM (unchanged, verified) -----------------------
template<int KS, int NTOT, int PNT, int MODE>
__global__ __launch_bounds__(256) void gemm_act(
    const unsigned short* __restrict__ A, const unsigned short* __restrict__ Bw,
    const float* __restrict__ bias, unsigned short* __restrict__ out){
  const int N = NTOT*16;
  int lane = threadIdx.x & 63;
  int wid  = threadIdx.x >> 6;
  int gw   = blockIdx.x*4 + wid;
  size_t rb = (size_t)gw*32;
  int lr = lane&15, lk = (lane>>4)<<3, lq = (lane>>4)<<2;
  u16x8 a[2][KS];
  #pragma unroll
  for (int mt=0; mt<2; ++mt)
    #pragma unroll
    for (int ks=0; ks<KS; ++ks)
      a[mt][ks] = *(const u16x8*)&A[(rb + mt*16 + lr)*(KS*32) + ks*32 + lk];
  #pragma unroll
  for (int p=0; p<NTOT/PNT; ++p){
    f32x4 acc[2][PNT];
    #pragma unroll
    for (int mt=0; mt<2; ++mt)
      #pragma unroll
      for (int i=0; i<PNT; ++i) acc[mt][i] = f32x4{0.f,0.f,0.f,0.f};
    #pragma unroll
    for (int ks=0; ks<KS; ++ks){
      #pragma unroll
      for (int i=0; i<PNT; ++i){
        int nt = p*PNT + i;
        u16x8 b = *(const u16x8*)&Bw[((size_t)(nt*KS + ks)*64 + lane)*8];
        acc[0][i] = mfma16(a[0][ks], b, acc[0][i]);
        acc[1][i] = mfma16(a[1][ks], b, acc[1][i]);
      }
    }
    #pragma unroll
    for (int i=0; i<PNT; ++i){
      int nt = p*PNT + i; int col = nt*16 + lr;
      float bv = bias[col];
      #pragma unroll
      for (int mt=0; mt<2; ++mt){
        #pragma unroll
        for (int q=0; q<4; ++q){
          size_t row = rb + mt*16 + lq + q;
          float v = acc[mt][i][q] + bv;
          if (MODE==1) v = __expf(-fmaxf(0.f, v));
          out[row*N + col] = f2bf(v);
        }
      }
    }
  }
}

// ---- persistent sequential kernel: split VGPR+LDS residency --------------
__global__ __launch_bounds__(512, 2) void seq6(
    const unsigned short* __restrict__ WrG, const unsigned short* __restrict__ WldsG,
    const unsigned short* __restrict__ WstrG,
    const unsigned short* __restrict__ gamma, const unsigned short* __restrict__ gipre,
    const float* __restrict__ bhh, float* __restrict__ out){
  extern __shared__ char smem[];
  unsigned short* Wlds = (unsigned short*)smem;            // 131072 B (ks3,4)
  unsigned short* hsw  = (unsigned short*)(smem + 131072); //   8192 B
  const int tid  = threadIdx.x;
  const int lane = tid & 63;
  const int w    = tid >> 6;              // 0..7
  const int bbase = blockIdx.x * 16;
  const int lr   = lane & 15;
  const int lq4  = (lane >> 4) << 2;

  // ---- prologue: VGPR-resident ks0..2 (24 chunks = 96 VGPRs), pinned ----
  u16x8 Wr[4][2][3];
  #pragma unroll
  for (int g=0; g<4; ++g)
    #pragma unroll
    for (int c=0; c<2; ++c)
      #pragma unroll
      for (int ks=0; ks<3; ++ks){
        Wr[g][c][ks] = *(const u16x8*)&WrG[(((w*8+g*2+c)*3+ks)*64 + lane)*8];
        asm volatile("" : "+v"(Wr[g][c][ks]));
      }

  // ---- prologue: LDS-resident ks3..4 (128 chunks = 128 KB) ----
  for (int i = tid; i < 8192; i += 512)
    *(u16x8*)&Wlds[i*8] = *(const u16x8*)&WldsG[i*8];

  float h_reg[2][4];
  #pragma unroll
  for (int c=0; c<2; ++c)
    #pragma unroll
    for (int q=0; q<4; ++q) h_reg[c][q] = 0.f;

  float bnv[2];
  #pragma unroll
  for (int c=0; c<2; ++c) bnv[c] = bhh[512 + w*32 + c*16 + lr];

  // hsw write addrs: element (row=lq4+q, hdim=col)
  int sh[2][4];
  #pragma unroll
  for (int c=0; c<2; ++c){
    const int col = w*32 + c*16 + lr;
    #pragma unroll
    for (int q=0; q<4; ++q)
      sh[c][q] = (col>>5)*512 + ((lq4+q) + (((col>>3)&3)<<4))*8 + (col&7);
  }

  unsigned short g_pre[2][4];
  #pragma unroll
  for (int c=0; c<2; ++c)
    #pragma unroll
    for (int q=0; q<4; ++q)
      g_pre[c][q] = gamma[((size_t)(bbase + lq4 + q))*256 + w*32 + c*16 + lr];

  const unsigned short* wsb = WstrG + (size_t)w*12288 + lane*8;

  __syncthreads();

  for (int t = 0; t < 128; ++t){
    // ---- phase 1: decay h, emit rep, publish A-fragments ----
    #pragma unroll
    for (int c=0; c<2; ++c){
      const int col = w*32 + c*16 + lr;
      #pragma unroll
      for (int q=0; q<4; ++q){
        float hd = h_reg[c][q] * bf2f(g_pre[c][q]);
        out[((size_t)(bbase+lq4+q)*128 + t)*256 + col] = hd;
        h_reg[c][q] = hd;
        hsw[sh[c][q]] = f2bf(hd);
      }
    }
    __syncthreads();   // S1: hsw ready

    // issue gipre loads early; consumed in gate phase (~3000 cy later)
    const unsigned short* gp = gipre + ((size_t)t*1024 + bbase)*768;
    unsigned short gv[3][2][4];
    #pragma unroll
    for (int g3=0; g3<3; ++g3)
      #pragma unroll
      for (int c=0; c<2; ++c)
        #pragma unroll
        for (int q=0; q<4; ++q)
          gv[g3][c][q] = gp[(size_t)(lq4+q)*768 + g3*256 + w*32 + c*16 + lr];

    f32x4 acc[4][2];
    #pragma unroll
    for (int g=0; g<4; ++g)
      #pragma unroll
      for (int c=0; c<2; ++c) acc[g][c] = f32x4{0.f,0.f,0.f,0.f};

    #define LD(v_, ksi_, g_, c_) \
      v_ = *(const u16x8*)(wsb + (((g_)*2+(c_))*3 + (ksi_))*512);
    #define MM(v_, a_, g_, c_) \
      acc[g_][c_] = mfma16(a_, v_, acc[g_][c_]); \
      __builtin_amdgcn_sched_barrier(0);

    // issue first 6 stream chunks (ks5: g0..2 x c0..1)
    u16x8 s0,s1,s2,s3,s4,s5;
    LD(s0, 0,0,0) LD(s1, 0,0,1) LD(s2, 0,1,0) LD(s3, 0,1,1) LD(s4, 0,2,0) LD(s5, 0,2,1)
    __builtin_amdgcn_sched_barrier(0);

    // resident ks0..2 from VGPR (24 MFMA) — overlaps in-flight stream loads
    #pragma unroll
    for (int ks=0; ks<3; ++ks){
      u16x8 aR = *(const u16x8*)&hsw[ks*512 + lane*8];
      #pragma unroll
      for (int g=0; g<4; ++g)
        #pragma unroll
        for (int c=0; c<2; ++c)
          acc[g][c] = mfma16(aR, Wr[g][c][ks], acc[g][c]);
    }
    // LDS-resident ks3..4 (16 MFMA)
    #pragma unroll
    for (int ks2=0; ks2<2; ++ks2){
      u16x8 aL = *(const u16x8*)&hsw[(3+ks2)*512 + lane*8];
      #pragma unroll
      for (int g=0; g<4; ++g)
        #pragma unroll
        for (int c=0; c<2; ++c){
          u16x8 bL = *(const u16x8*)&Wlds[((w*8+g*2+c)*2 + ks2)*512 + lane*8];
          acc[g][c] = mfma16(aL, bL, acc[g][c]);
        }
    }

    // streamed ks5..7 (24 MFMA), 6-deep rolling buffer
    {
      u16x8 a5 = *(const u16x8*)&hsw[5*512 + lane*8];
      MM(s0, a5,0,0) LD(s0, 0,3,0)
      MM(s1, a5,0,1) LD(s1, 0,3,1)
      MM(s2, a5,1,0) LD(s2, 1,0,0)
      MM(s3, a5,1,1) LD(s3, 1,0,1)
      MM(s4, a5,2,0) LD(s4, 1,1,0)
      MM(s5, a5,2,1) LD(s5, 1,1,1)
      MM(s0, a5,3,0) LD(s0, 1,2,0)
      MM(s1, a5,3,1) LD(s1, 1,2,1)
      u16x8 a6 = *(const u16x8*)&hsw[6*512 + lane*8];
      MM(s2, a6,0,0) LD(s2, 1,3,0)
      MM(s3, a6,0,1) LD(s3, 1,3,1)
      MM(s4, a6,1,0) LD(s4, 2,0,0)
      MM(s5, a6,1,1) LD(s5, 2,0,1)
      MM(s0, a6,2,0) LD(s0, 2,1,0)
      MM(s1, a6,2,1) LD(s1, 2,1,1)
      MM(s2, a6,3,0) LD(s2, 2,2,0)
      MM(s3, a6,3,1) LD(s3, 2,2,1)
      u16x8 a7 = *(const u16x8*)&hsw[7*512 + lane*8];
      MM(s4, a7,0,0) LD(s4, 2,3,0)
      MM(s5, a7,0,1) LD(s5, 2,3,1)
      MM(s0, a7,1,0)
      MM(s1, a7,1,1)
      MM(s2, a7,2,0)
      MM(s3, a7,2,1)
      MM(s4, a7,3,0)
      MM(s5, a7,3,1)
    }
    #undef LD
    #undef MM
    __syncthreads();   // S2: hsw reads done -> next phase1 may overwrite

    // ---- gate phase (in-register) ----
    #pragma unroll
    for (int c=0; c<2; ++c){
      const int col = w*32 + c*16 + lr;
      #pragma unroll
      for (int q=0; q<4; ++q){
        float gr = bf2f(gv[0][c][q]);
        float gz = bf2f(gv[1][c][q]);
        float gn = bf2f(gv[2][c][q]);
        float rr = sigm(gr + acc[0][c][q]);
        float zz = sigm(gz + acc[1][c][q]);
        float nv = tanh_f(gn + acc[2][c][q] + rr*(acc[3][c][q] + bnv[c]));
        float hn = (1.f-zz)*nv + zz*h_reg[c][q];
        h_reg[c][q] = hn;
        if (t == 127) out[(size_t)33554432 + (size_t)(bbase+lq4+q)*256 + col] = hn;
      }
    }
    // prefetch next step's gamma
    if (t < 127){
      #pragma unroll
      for (int c=0; c<2; ++c)
        #pragma unroll
        for (int q=0; q<4; ++q)
          g_pre[c][q] = gamma[((size_t)(t+1)*1024 + bbase + lq4 + q)*256 + w*32 + c*16 + lr];
    }
  }
}

// ---- host glue -----------------------------------------------------------
extern "C" void kernel_launch(void* const* d_in, const int* in_sizes, int n_in,
                              void* d_out, int out_size, void* d_ws, size_t ws_size,
                              hipStream_t stream){
  (void)in_sizes; (void)n_in; (void)out_size; (void)ws_size;
  const float* X   = (const float*)d_in[0];
  const float* M   = (const float*)d_in[1];
  const float* D   = (const float*)d_in[2];
  const float* mu  = (const float*)d_in[3];
  const float* Xl  = (const float*)d_in[4];
  const float* Wdh = (const float*)d_in[5];
  const float* bdh = (const float*)d_in[6];
  const float* Wdx = (const float*)d_in[7];
  const float* bdx = (const float*)d_in[8];
  const float* Wih = (const float*)d_in[9];
  const float* Whh = (const float*)d_in[10];
  const float* bih = (const float*)d_in[11];
  const float* bhh = (const float*)d_in[12];
  float* out = (float*)d_out;
  char* ws = (char*)d_ws;

  // workspace layout
  unsigned short* gipre = (unsigned short*)ws;                      // 201326592 B
  unsigned short* gamma = (unsigned short*)(ws + 201326592);        //  67108864 B
  unsigned short* W2sw  = (unsigned short*)(ws + 268435456);        //    393216 B
  unsigned short* Wdsw  = (unsigned short*)(ws + 268828672);        //     65536 B
  unsigned short* WrG   = (unsigned short*)(ws + 268894208);        //    196608 B
  unsigned short* WldsG = (unsigned short*)(ws + 269090816);        //    131072 B
  unsigned short* WstrG = (unsigned short*)(ws + 269221888);        //    196608 B
  float*          b2    = (float*)        (ws + 269418496);         //      3072 B
  // Apre (67.1MB) + Dt (33.6MB) staged inside d_out: fully consumed by the
  // GEMMs below BEFORE seq6 writes the real outputs (same-stream ordering).
  unsigned short* Apre = (unsigned short*)d_out;
  unsigned short* Dt   = (unsigned short*)((char*)d_out + 67108864);

  hipFuncSetAttribute(reinterpret_cast<const void*>(seq6),
                      hipFuncAttributeMaxDynamicSharedMemorySize, 139264);

  kw<<<256, 256, 0, stream>>>(Wdh, Wih, Whh, bih, bhh, WrG, WldsG, WstrG, W2sw, Wdsw, b2);
  kprep<<<1024, 256, 0, stream>>>(X, M, D, mu, Xl, Wdx, bdx, Apre, Dt);
  gemm_act<4,16,8,1><<<1024, 256, 0, stream>>>(Dt, Wdsw, bdh, gamma);
  gemm_act<8,48,8,0><<<1024, 256, 0, stream>>>(Apre, W2sw, b2, gipre);
  seq6<<<64, 512, 139264, stream>>>(WrG, WldsG, WstrG, gamma, gipre, bhh, out);
}

// Round 9
// 1277.612 us; speedup vs baseline: 1.5468x; 1.0114x over previous
//
#include <hip/hip_runtime.h>
#include <cstdint>
#include <cstddef>

typedef __attribute__((ext_vector_type(8))) __bf16 bf16x8;
typedef __attribute__((ext_vector_type(8))) unsigned short u16x8;
typedef __attribute__((ext_vector_type(4))) unsigned short u16x4;
typedef __attribute__((ext_vector_type(2))) unsigned short u16x2;
typedef __attribute__((ext_vector_type(4))) float f32x4;
typedef __attribute__((ext_vector_type(2))) float f32x2;

// ---- helpers -------------------------------------------------------------
__device__ __forceinline__ unsigned short f2bf(float f){
  unsigned int u = __float_as_uint(f);
  u += 0x7FFFu + ((u >> 16) & 1u);          // round to nearest even
  return (unsigned short)(u >> 16);
}
__device__ __forceinline__ float bf2f(unsigned short s){
  return __uint_as_float(((unsigned int)s) << 16);
}
__device__ __forceinline__ float sigm(float x){ return 1.f/(1.f + __expf(-x)); }
__device__ __forceinline__ float tanh_f(float x){ float e = __expf(2.f*x); return 1.f - 2.f/(e + 1.f); }
__device__ __forceinline__ f32x4 mfma16(u16x8 a, u16x8 b, f32x4 c){
  return __builtin_amdgcn_mfma_f32_16x16x32_bf16(
      __builtin_bit_cast(bf16x8, a), __builtin_bit_cast(bf16x8, b), c, 0, 0, 0);
}

// B=1024, T=128, F=128, H=256
// Per step: S = h(16x256 per WG) @ Wc(256x1024); gate g cols [g*256,(g+1)*256):
//   g=0: Wih_h_r + Whh_r ; g=1: Wih_h_z + Whh_z ; g=2: Wih_h_n ; g=3: Whh_n
// seq7: 64 WGs x 512 thr (8 waves), 16 rows/WG, 1 WG/CU.
//   amdgpu_waves_per_eu(2,2): allocator gets the FULL 256-reg budget
//   (round 8: VGPR_Count=128 proved the allocator demoted the pinned
//   weights to chase 4 waves/EU; step time tracked streamed bytes).
//   Residency: ks0..3 VGPR (32 chunks = 128 regs/wave, pinned)
//              ks4..5 LDS (128 chunks = 128 KB, loaded once)
//   Streamed:  ks6..7 (128 KB/step/CU), 4-deep rolling register buffer.

__device__ __forceinline__ float wcval(int g, int n, int k,
    const float* __restrict__ Wih, const float* __restrict__ Whh){
  if (g==0) return Wih[n*512 + 128+k]       + Whh[n*256 + k];
  if (g==1) return Wih[(256+n)*512 + 128+k] + Whh[(256+n)*256 + k];
  if (g==2) return Wih[(512+n)*512 + 128+k];
  return Whh[(512+n)*256 + k];
}

// ---- weight prep ---------------------------------------------------------
// WrG  : (((w*8+g*2+c)*4+ks )*64+l)*8+j  ks=0..3  (131072 elems, 256 KB)
// WldsG: (((w*8+g*2+c)*2+ks2)*64+l)*8+j  ks=4+ks2 ( 65536 elems, 128 KB)
// WstrG: ((w*16+ksi*8+g*2+c)*64+l)*8+j   ks=6+ksi ( 65536 elems, 128 KB)
// all with n = (w*2+c)*16 + (l&15) [within-gate col], k = ks*32+((l>>4)<<3)+j
__global__ __launch_bounds__(256) void kw(
    const float* __restrict__ Wdh, const float* __restrict__ Wih,
    const float* __restrict__ Whh, const float* __restrict__ bih,
    const float* __restrict__ bhh,
    unsigned short* __restrict__ WrG, unsigned short* __restrict__ WldsG,
    unsigned short* __restrict__ WstrG,
    unsigned short* __restrict__ W2,
    unsigned short* __restrict__ Wd, float* __restrict__ b2){
  int i0 = blockIdx.x*256 + threadIdx.x;
  int stride = gridDim.x*256;
  for (int idx=i0; idx<131072; idx+=stride){          // WrG (ks 0..3)
    int j=idx&7, l=(idx>>3)&63, r=idx>>9;             // r < 256
    int ks=r&3, r2=r>>2;                              // r2 = w*8+g*2+c
    int c=r2&1, g=(r2>>1)&3, w=r2>>3;
    int n = (w*2+c)*16 + (l&15);
    int k = ks*32 + ((l>>4)<<3) + j;
    WrG[idx] = f2bf(wcval(g, n, k, Wih, Whh));
  }
  for (int idx=i0; idx<65536; idx+=stride){           // WldsG (ks 4..5)
    int j=idx&7, l=(idx>>3)&63, r=idx>>9;             // r < 128
    int ks2=r&1, r2=r>>1;
    int c=r2&1, g=(r2>>1)&3, w=r2>>3;
    int n = (w*2+c)*16 + (l&15);
    int k = (4+ks2)*32 + ((l>>4)<<3) + j;
    WldsG[idx] = f2bf(wcval(g, n, k, Wih, Whh));
  }
  for (int idx=i0; idx<65536; idx+=stride){           // WstrG (ks 6..7)
    int j=idx&7, l=(idx>>3)&63, r=idx>>9;             // r < 128
    int ch=r&15, w=r>>4;                              // ch = ksi*8+g*2+c
    int c=ch&1, g=(ch>>1)&3, ksi=ch>>3;
    int n = (w*2+c)*16 + (l&15);
    int k = (6+ksi)*32 + ((l>>4)<<3) + j;
    WstrG[idx] = f2bf(wcval(g, n, k, Wih, Whh));
  }
  for (int idx=i0; idx<196608; idx+=stride){
    int j=idx&7, l=(idx>>3)&63, ks=(idx>>9)&7, nt=idx>>12;
    int n = nt*16 + (l&15);
    int k = ks*32 + ((l>>4)<<3) + j;
    float v = (k<128) ? Wih[n*512 + k] : Wih[n*512 + 256 + k];
    W2[idx] = f2bf(v);
  }
  for (int idx=i0; idx<32768; idx+=stride){
    int j=idx&7, l=(idx>>3)&63, ks=(idx>>9)&3, nt=idx>>11;
    int n = nt*16 + (l&15);
    int k = ks*32 + ((l>>4)<<3) + j;
    Wd[idx] = f2bf(Wdh[n*128 + k]);
  }
  for (int idx=i0; idx<768; idx+=stride)
    b2[idx] = bih[idx] + (idx<512 ? bhh[idx] : 0.f);
}

// ---- elementwise prep: Apre=[x_in|m] (T,B,256) bf16 ; Dt=(T,B,128) bf16 --
__global__ __launch_bounds__(256) void kprep(
    const float* __restrict__ X, const float* __restrict__ M,
    const float* __restrict__ D, const float* __restrict__ mu,
    const float* __restrict__ Xl, const float* __restrict__ Wdx,
    const float* __restrict__ bdx,
    unsigned short* __restrict__ Apre, unsigned short* __restrict__ Dt){
  int lane = threadIdx.x & 63;
  int wave = (blockIdx.x*256 + threadIdx.x) >> 6;
  int c0 = lane*2;
  float dg0 = Wdx[c0*128 + c0];
  float dg1 = Wdx[(c0+1)*128 + (c0+1)];
  float bx0 = bdx[c0], bx1 = bdx[c0+1];
  for (int r = wave; r < 131072; r += 4096){
    int t = r>>10, b = r&1023;
    size_t src = ((size_t)b*128 + t)*128 + c0;
    f32x2 x  = *(const f32x2*)(X+src);
    f32x2 m  = *(const f32x2*)(M+src);
    f32x2 d  = *(const f32x2*)(D+src);
    f32x2 xl = *(const f32x2*)(Xl+src);
    f32x2 mb = *(const f32x2*)(mu + b*128 + c0);
    float g0 = __expf(-fmaxf(0.f, d.x*dg0 + bx0));
    float g1 = __expf(-fmaxf(0.f, d.y*dg1 + bx1));
    float xh0 = g0*xl.x + (1.f-g0)*mb.x;
    float xh1 = g1*xl.y + (1.f-g1)*mb.y;
    float xi0 = m.x*x.x + (1.f-m.x)*xh0;
    float xi1 = m.y*x.y + (1.f-m.y)*xh1;
    size_t ar = (size_t)r*256;
    *(u16x2*)(Apre + ar + c0)        = u16x2{f2bf(xi0), f2bf(xi1)};
    *(u16x2*)(Apre + ar + 128 + c0)  = u16x2{f2bf(m.x), f2bf(m.y)};
    *(u16x2*)(Dt + (size_t)r*128 + c0) = u16x2{f2bf(d.x), f2bf(d.y)};
  }
}

// ---- batched activation GEMM (unchanged, verified) -----------------------
template<int KS, int NTOT, int PNT, int MODE>
__global__ __launch_bounds__(256) void gemm_act(
    const unsigned short* __restrict__ A, const unsigned short* __restrict__ Bw,
    const float* __restrict__ bias, unsigned short* __restrict__ out){
  const int N = NTOT*16;
  int lane = threadIdx.x & 63;
  int wid  = threadIdx.x >> 6;
  int gw   = blockIdx.x*4 + wid;
  size_t rb = (size_t)gw*32;
  int lr = lane&15, lk = (lane>>4)<<3, lq = (lane>>4)<<2;
  u16x8 a[2][KS];
  #pragma unroll
  for (int mt=0; mt<2; ++mt)
    #pragma unroll
    for (int ks=0; ks<KS; ++ks)
      a[mt][ks] = *(const u16x8*)&A[(rb + mt*16 + lr)*(KS*32) + ks*32 + lk];
  #pragma unroll
  for (int p=0; p<NTOT/PNT; ++p){
    f32x4 acc[2][PNT];
    #pragma unroll
    for (int mt=0; mt<2; ++mt)
      #pragma unroll
      for (int i=0; i<PNT; ++i) acc[mt][i] = f32x4{0.f,0.f,0.f,0.f};
    #pragma unroll
    for (int ks=0; ks<KS; ++ks){
      #pragma unroll
      for (int i=0; i<PNT; ++i){
        int nt = p*PNT + i;
        u16x8 b = *(const u16x8*)&Bw[((size_t)(nt*KS + ks)*64 + lane)*8];
        acc[0][i] = mfma16(a[0][ks], b, acc[0][i]);
        acc[1][i] = mfma16(a[1][ks], b, acc[1][i]);
      }
    }
    #pragma unroll
    for (int i=0; i<PNT; ++i){
      int nt = p*PNT + i; int col = nt*16 + lr;
      float bv = bias[col];
      #pragma unroll
      for (int mt=0; mt<2; ++mt){
        #pragma unroll
        for (int q=0; q<4; ++q){
          size_t row = rb + mt*16 + lq + q;
          float v = acc[mt][i][q] + bv;
          if (MODE==1) v = __expf(-fmaxf(0.f, v));
          out[row*N + col] = f2bf(v);
        }
      }
    }
  }
}

// ---- persistent sequential kernel: pinned-occupancy split residency ------
__global__ __launch_bounds__(512)
__attribute__((amdgpu_waves_per_eu(2, 2)))
void seq7(
    const unsigned short* __restrict__ WrG, const unsigned short* __restrict__ WldsG,
    const unsigned short* __restrict__ WstrG,
    const unsigned short* __restrict__ gamma, const unsigned short* __restrict__ gipre,
    const float* __restrict__ bhh, float* __restrict__ out){
  extern __shared__ char smem[];
  unsigned short* Wlds = (unsigned short*)smem;            // 131072 B (ks4,5)
  unsigned short* hsw  = (unsigned short*)(smem + 131072); //   8192 B
  const int tid  = threadIdx.x;
  const int lane = tid & 63;
  const int w    = tid >> 6;              // 0..7
  const int bbase = blockIdx.x * 16;
  const int lr   = lane & 15;
  const int lq4  = (lane >> 4) << 2;

  // ---- prologue: VGPR-resident ks0..3 (32 chunks = 128 VGPRs), pinned ----
  u16x8 Wr[4][2][4];
  #pragma unroll
  for (int g=0; g<4; ++g)
    #pragma unroll
    for (int c=0; c<2; ++c)
      #pragma unroll
      for (int ks=0; ks<4; ++ks){
        Wr[g][c][ks] = *(const u16x8*)&WrG[(((w*8+g*2+c)*4+ks)*64 + lane)*8];
        asm volatile("" : "+v"(Wr[g][c][ks]));
      }

  // ---- prologue: LDS-resident ks4..5 (128 chunks = 128 KB) ----
  for (int i = tid; i < 8192; i += 512)
    *(u16x8*)&Wlds[i*8] = *(const u16x8*)&WldsG[i*8];

  float h_reg[2][4];
  #pragma unroll
  for (int c=0; c<2; ++c)
    #pragma unroll
    for (int q=0; q<4; ++q) h_reg[c][q] = 0.f;

  float bnv[2];
  #pragma unroll
  for (int c=0; c<2; ++c) bnv[c] = bhh[512 + w*32 + c*16 + lr];

  unsigned short g_pre[2][4];
  #pragma unroll
  for (int c=0; c<2; ++c)
    #pragma unroll
    for (int q=0; q<4; ++q)
      g_pre[c][q] = gamma[((size_t)(bbase + lq4 + q))*256 + w*32 + c*16 + lr];

  const unsigned short* wsb = WstrG + (size_t)w*8192 + lane*8;

  __syncthreads();

  for (int t = 0; t < 128; ++t){
    // ---- phase 1: decay h, publish A-fragments (stores deferred) ----
    #pragma unroll
    for (int c=0; c<2; ++c){
      const int col = w*32 + c*16 + lr;
      #pragma unroll
      for (int q=0; q<4; ++q){
        float hd = h_reg[c][q] * bf2f(g_pre[c][q]);
        h_reg[c][q] = hd;
        hsw[(col>>5)*512 + ((lq4+q) + (((col>>3)&3)<<4))*8 + (col&7)] = f2bf(hd);
      }
    }
    __syncthreads();   // S1: hsw ready (only LDS writes pending here)

    // rep stores AFTER the barrier: drain overlaps the MFMA phase
    #pragma unroll
    for (int c=0; c<2; ++c){
      const int col = w*32 + c*16 + lr;
      #pragma unroll
      for (int q=0; q<4; ++q)
        out[((size_t)(bbase+lq4+q)*128 + t)*256 + col] = h_reg[c][q];
    }

    // gipre loads issued early; consumed in gate phase
    const unsigned short* gp = gipre + ((size_t)t*1024 + bbase)*768;
    unsigned short gv[3][2][4];
    #pragma unroll
    for (int g3=0; g3<3; ++g3)
      #pragma unroll
      for (int c=0; c<2; ++c)
        #pragma unroll
        for (int q=0; q<4; ++q)
          gv[g3][c][q] = gp[(size_t)(lq4+q)*768 + g3*256 + w*32 + c*16 + lr];

    f32x4 acc[4][2];
    #pragma unroll
    for (int g=0; g<4; ++g)
      #pragma unroll
      for (int c=0; c<2; ++c) acc[g][c] = f32x4{0.f,0.f,0.f,0.f};

    #define LD(v_, ksi_, g_, c_) \
      v_ = *(const u16x8*)(wsb + ((ksi_)*8+(g_)*2+(c_))*512);
    #define MM(v_, a_, g_, c_) \
      acc[g_][c_] = mfma16(a_, v_, acc[g_][c_]); \
      __builtin_amdgcn_sched_barrier(0);

    // issue first 4 stream chunks (ks6: g0..1 x c0..1)
    u16x8 s0,s1,s2,s3;
    LD(s0, 0,0,0) LD(s1, 0,0,1) LD(s2, 0,1,0) LD(s3, 0,1,1)
    __builtin_amdgcn_sched_barrier(0);

    // resident ks0..3 from VGPR (32 MFMA) — overlaps in-flight stream loads
    #pragma unroll
    for (int ks=0; ks<4; ++ks){
      u16x8 aR = *(const u16x8*)&hsw[ks*512 + lane*8];
      #pragma unroll
      for (int g=0; g<4; ++g)
        #pragma unroll
        for (int c=0; c<2; ++c)
          acc[g][c] = mfma16(aR, Wr[g][c][ks], acc[g][c]);
    }
    // LDS-resident ks4..5 (16 MFMA)
    #pragma unroll
    for (int ks2=0; ks2<2; ++ks2){
      u16x8 aL = *(const u16x8*)&hsw[(4+ks2)*512 + lane*8];
      #pragma unroll
      for (int g=0; g<4; ++g)
        #pragma unroll
        for (int c=0; c<2; ++c){
          u16x8 bL = *(const u16x8*)&Wlds[((w*8+g*2+c)*2 + ks2)*512 + lane*8];
          acc[g][c] = mfma16(aL, bL, acc[g][c]);
        }
    }

    // streamed ks6..7 (16 MFMA), 4-deep rolling buffer
    {
      u16x8 a6 = *(const u16x8*)&hsw[6*512 + lane*8];
      MM(s0, a6,0,0) LD(s0, 0,2,0)
      MM(s1, a6,0,1) LD(s1, 0,2,1)
      MM(s2, a6,1,0) LD(s2, 0,3,0)
      MM(s3, a6,1,1) LD(s3, 0,3,1)
      MM(s0, a6,2,0) LD(s0, 1,0,0)
      MM(s1, a6,2,1) LD(s1, 1,0,1)
      MM(s2, a6,3,0) LD(s2, 1,1,0)
      MM(s3, a6,3,1) LD(s3, 1,1,1)
      u16x8 a7 = *(const u16x8*)&hsw[7*512 + lane*8];
      MM(s0, a7,0,0) LD(s0, 1,2,0)
      MM(s1, a7,0,1) LD(s1, 1,2,1)
      MM(s2, a7,1,0) LD(s2, 1,3,0)
      MM(s3, a7,1,1) LD(s3, 1,3,1)
      MM(s0, a7,2,0)
      MM(s1, a7,2,1)
      MM(s2, a7,3,0)
      MM(s3, a7,3,1)
    }
    #undef LD
    #undef MM
    __syncthreads();   // S2: hsw reads done -> next phase1 may overwrite

    // ---- gate phase (in-register) ----
    #pragma unroll
    for (int c=0; c<2; ++c){
      const int col = w*32 + c*16 + lr;
      #pragma unroll
      for (int q=0; q<4; ++q){
        float gr = bf2f(gv[0][c][q]);
        float gz = bf2f(gv[1][c][q]);
        float gn = bf2f(gv[2][c][q]);
        float rr = sigm(gr + acc[0][c][q]);
        float zz = sigm(gz + acc[1][c][q]);
        float nv = tanh_f(gn + acc[2][c][q] + rr*(acc[3][c][q] + bnv[c]));
        float hn = (1.f-zz)*nv + zz*h_reg[c][q];
        h_reg[c][q] = hn;
        if (t == 127) out[(size_t)33554432 + (size_t)(bbase+lq4+q)*256 + col] = hn;
      }
    }
    // prefetch next step's gamma
    if (t < 127){
      #pragma unroll
      for (int c=0; c<2; ++c)
        #pragma unroll
        for (int q=0; q<4; ++q)
          g_pre[c][q] = gamma[((size_t)(t+1)*1024 + bbase + lq4 + q)*256 + w*32 + c*16 + lr];
    }
  }
}

// ---- host glue -----------------------------------------------------------
extern "C" void kernel_launch(void* const* d_in, const int* in_sizes, int n_in,
                              void* d_out, int out_size, void* d_ws, size_t ws_size,
                              hipStream_t stream){
  (void)in_sizes; (void)n_in; (void)out_size; (void)ws_size;
  const float* X   = (const float*)d_in[0];
  const float* M   = (const float*)d_in[1];
  const float* D   = (const float*)d_in[2];
  const float* mu  = (const float*)d_in[3];
  const float* Xl  = (const float*)d_in[4];
  const float* Wdh = (const float*)d_in[5];
  const float* bdh = (const float*)d_in[6];
  const float* Wdx = (const float*)d_in[7];
  const float* bdx = (const float*)d_in[8];
  const float* Wih = (const float*)d_in[9];
  const float* Whh = (const float*)d_in[10];
  const float* bih = (const float*)d_in[11];
  const float* bhh = (const float*)d_in[12];
  float* out = (float*)d_out;
  char* ws = (char*)d_ws;

  // workspace layout
  unsigned short* gipre = (unsigned short*)ws;                      // 201326592 B
  unsigned short* gamma = (unsigned short*)(ws + 201326592);        //  67108864 B
  unsigned short* W2sw  = (unsigned short*)(ws + 268435456);        //    393216 B
  unsigned short* Wdsw  = (unsigned short*)(ws + 268828672);        //     65536 B
  unsigned short* WrG   = (unsigned short*)(ws + 268894208);        //    262144 B
  unsigned short* WldsG = (unsigned short*)(ws + 269156352);        //    131072 B
  unsigned short* WstrG = (unsigned short*)(ws + 269287424);        //    131072 B
  float*          b2    = (float*)        (ws + 269418496);         //      3072 B
  // Apre (67.1MB) + Dt (33.6MB) staged inside d_out: fully consumed by the
  // GEMMs below BEFORE seq7 writes the real outputs (same-stream ordering).
  unsigned short* Apre = (unsigned short*)d_out;
  unsigned short* Dt   = (unsigned short*)((char*)d_out + 67108864);

  hipFuncSetAttribute(reinterpret_cast<const void*>(seq7),
                      hipFuncAttributeMaxDynamicSharedMemorySize, 139264);

  kw<<<256, 256, 0, stream>>>(Wdh, Wih, Whh, bih, bhh, WrG, WldsG, WstrG, W2sw, Wdsw, b2);
  kprep<<<1024, 256, 0, stream>>>(X, M, D, mu, Xl, Wdx, bdx, Apre, Dt);
  gemm_act<4,16,8,1><<<1024, 256, 0, stream>>>(Dt, Wdsw, bdh, gamma);
  gemm_act<8,48,8,0><<<1024, 256, 0, stream>>>(Apre, W2sw, b2, gipre);
  seq7<<<64, 512, 139264, stream>>>(WrG, WldsG, WstrG, gamma, gipre, bhh, out);
}